// Round 8
// baseline (318.057 us; speedup 1.0000x reference)
//
#include <hip/hip_runtime.h>
#include <hip/hip_bf16.h>
#include <math.h>

#define THREADS 256
typedef unsigned short ushortT;
typedef __attribute__((ext_vector_type(8))) short bf16x8;   // 8 bf16 = 4 VGPRs
typedef __attribute__((ext_vector_type(4))) float f32x4;

__device__ __forceinline__ void async16(const ushortT* g, ushortT* l) {
  __builtin_amdgcn_global_load_lds(
      (const __attribute__((address_space(1))) unsigned int*)g,
      (__attribute__((address_space(3))) unsigned int*)l, 16, 0, 0);
}

__device__ __forceinline__ ushortT f2bf(float f) {
  __hip_bfloat16 h = __float2bfloat16(f);
  return *reinterpret_cast<ushortT*>(&h);
}

// ---------------------------------------------------------------------------
// Kernel A: fused L2-norm + bf16 convert. One block per row. Block 0 also
// zero-inits the global accumulators used by k_reduce_final (ws is poisoned
// 0xAA before every launch; kernel-boundary ordering on the stream makes
// this visible to k_reduce_final).
// ---------------------------------------------------------------------------
__global__ __launch_bounds__(THREADS) void k_prep(const float* __restrict__ x,
                                                  ushortT* __restrict__ xn,
                                                  float* __restrict__ accums, int D) {
  __shared__ float red[4];
  const int row = blockIdx.x;
  const int tid = threadIdx.x;
  if (row == 0 && tid == 0) {
    accums[0] = 0.f;                       // loss sum
    accums[1] = 0.f;                       // valid count
    reinterpret_cast<int*>(accums)[2] = 0; // done-block counter
  }
  const int gid = row * (D / 4) + tid;
  const float4 v = reinterpret_cast<const float4*>(x)[gid];
  float s = v.x * v.x + v.y * v.y + v.z * v.z + v.w * v.w;
  #pragma unroll
  for (int off = 32; off; off >>= 1) s += __shfl_xor(s, off);
  if ((tid & 63) == 0) red[tid >> 6] = s;
  __syncthreads();
  const float tot = red[0] + red[1] + red[2] + red[3];
  const float rn = 1.0f / fmaxf(sqrtf(tot), 1e-12f);
  ushort4 o;
  o.x = f2bf(v.x * rn); o.y = f2bf(v.y * rn);
  o.z = f2bf(v.z * rn); o.w = f2bf(v.w * rn);
  reinterpret_cast<ushort4*>(xn)[gid] = o;
}

// ---------------------------------------------------------------------------
// Kernel B: triangular 128x128 bf16 MFMA tiles, BK=64 single LDS buffer
// (32 KB), register-staged fragments:
//   per kiter: ds_read ALL 16 frags -> barrier (buffer free) -> issue next
//   stage -> 32 MFMAs while the stage is in flight -> barrier (vmcnt drain
//   now overlapped by the MFMA burst). 16 kiters instead of 32 halves the
//   barrier-drain count vs R3.
// Staging in fragment-read order (lane*16B = row lane&15, chunk lane>>4)
// -> ds_read_b128 conflict-free. Diagonal blocks stage A only (B==A).
// Dual-orientation circle-loss epilogue (R3's, no spill).
// partial[(row*nb + cb)*2 + half] = {m, sp, 0, sn}
// ---------------------------------------------------------------------------
__global__ __launch_bounds__(THREADS, 2) void k_main_mfma(const ushortT* __restrict__ xn,
                                                          const int* __restrict__ tgt,
                                                          float4* __restrict__ partial,
                                                          int D, int nb) {
  __shared__ ushortT Asm[16 * 512];  // 16 KB: 128 rows x 64 k (2 halves x 8 groups)
  __shared__ ushortT Bsm[16 * 512];  // 16 KB

  const int tid = threadIdx.x;
  const int lane = tid & 63;
  const int w = tid >> 6;

  // --- triangular decode: b -> (bi, bj), bi <= bj
  const int b = blockIdx.x;
  int bi = (int)((2.f * nb + 1.f -
                  sqrtf((2.f * nb + 1.f) * (2.f * nb + 1.f) - 8.f * (float)b)) * 0.5f);
  while ((bi + 1) * (2 * nb - bi) / 2 <= b) ++bi;
  while (bi * (2 * nb - bi + 1) / 2 > b) --bi;
  const int bj = bi + (b - bi * (2 * nb - bi + 1) / 2);
  const bool isdiag = (bi == bj);

  const int i0 = bi * 128, j0 = bj * 128;
  const int wr = (w >> 1) * 64, wc = (w & 1) * 64;

  // --- staging: lane fetches (row = lane&15, chunk = lane>>4) of its group.
  // Wave w stages A groups {w, w+4} and B groups {w, w+4}, both 32-k halves.
  const int sr = lane & 15, sc = lane >> 4;
  const ushortT* gA0 = xn + (size_t)(i0 + 16 * w + sr) * D + sc * 8;
  const ushortT* gA1 = gA0 + (size_t)64 * D;
  const ushortT* gB0 = xn + (size_t)(j0 + 16 * w + sr) * D + sc * 8;
  const ushortT* gB1 = gB0 + (size_t)64 * D;
  // LDS chunk for (group g, half h) = (h*8 + g)*512 ushorts.
  ushortT* lA[4] = {&Asm[(0 * 8 + w) * 512], &Asm[(1 * 8 + w) * 512],
                    &Asm[(0 * 8 + w + 4) * 512], &Asm[(1 * 8 + w + 4) * 512]};
  ushortT* lB[4] = {&Bsm[(0 * 8 + w) * 512], &Bsm[(1 * 8 + w) * 512],
                    &Bsm[(0 * 8 + w + 4) * 512], &Bsm[(1 * 8 + w + 4) * 512]};

  f32x4 acc[4][4];
  #pragma unroll
  for (int mt = 0; mt < 4; ++mt)
    #pragma unroll
    for (int nt = 0; nt < 4; ++nt)
      acc[mt][nt] = (f32x4){0.f, 0.f, 0.f, 0.f};

  const ushortT* Bb = isdiag ? Asm : Bsm;
  const int ag = 4 * (w >> 1);   // A group base for this wave's rows
  const int bg = 4 * (w & 1);    // B group base for this wave's cols

  // prologue: stage kt=0
  async16(gA0, lA[0]); async16(gA0 + 32, lA[1]);
  async16(gA1, lA[2]); async16(gA1 + 32, lA[3]);
  if (!isdiag) {
    async16(gB0, lB[0]); async16(gB0 + 32, lB[1]);
    async16(gB1, lB[2]); async16(gB1 + 32, lB[3]);
  }
  __syncthreads();

  const int kiters = D / 64;  // 16
  for (int kt = 0; kt < kiters; ++kt) {
    // read ALL fragments for both 32-k halves into registers
    bf16x8 a0[4], b0[4], a1[4], b1[4];
    #pragma unroll
    for (int mt = 0; mt < 4; ++mt) {
      a0[mt] = *reinterpret_cast<const bf16x8*>(&Asm[(0 * 8 + ag + mt) * 512 + lane * 8]);
      a1[mt] = *reinterpret_cast<const bf16x8*>(&Asm[(1 * 8 + ag + mt) * 512 + lane * 8]);
    }
    #pragma unroll
    for (int nt = 0; nt < 4; ++nt) {
      b0[nt] = *reinterpret_cast<const bf16x8*>(&Bb[(0 * 8 + bg + nt) * 512 + lane * 8]);
      b1[nt] = *reinterpret_cast<const bf16x8*>(&Bb[(1 * 8 + bg + nt) * 512 + lane * 8]);
    }
    __syncthreads();            // all waves done reading -> buffer free
    if (kt + 1 < kiters) {      // issue next stage; MFMAs below cover flight
      const size_t ko = (size_t)(kt + 1) * 64;
      async16(gA0 + ko, lA[0]); async16(gA0 + ko + 32, lA[1]);
      async16(gA1 + ko, lA[2]); async16(gA1 + ko + 32, lA[3]);
      if (!isdiag) {
        async16(gB0 + ko, lB[0]); async16(gB0 + ko + 32, lB[1]);
        async16(gB1 + ko, lB[2]); async16(gB1 + ko + 32, lB[3]);
      }
    }
    #pragma unroll
    for (int mt = 0; mt < 4; ++mt)
      #pragma unroll
      for (int nt = 0; nt < 4; ++nt)
        acc[mt][nt] = __builtin_amdgcn_mfma_f32_16x16x32_bf16(a0[mt], b0[nt], acc[mt][nt], 0, 0, 0);
    #pragma unroll
    for (int mt = 0; mt < 4; ++mt)
      #pragma unroll
      for (int nt = 0; nt < 4; ++nt)
        acc[mt][nt] = __builtin_amdgcn_mfma_f32_16x16x32_bf16(a1[mt], b1[nt], acc[mt][nt], 0, 0, 0);
    __syncthreads();            // staged data visible for next read
  }

  // --- epilogue. C/D layout: col = lane&15, row = (lane>>4)*4 + reg
  const int q = lane >> 4, c = lane & 15;
  int tj[4];
  #pragma unroll
  for (int nt = 0; nt < 4; ++nt) tj[nt] = tgt[j0 + wc + nt * 16 + c];
  int tir[16];
  #pragma unroll
  for (int mt = 0; mt < 4; ++mt) {
    const int4 t4 = *reinterpret_cast<const int4*>(tgt + i0 + wr + mt * 16 + q * 4);
    tir[mt * 4 + 0] = t4.x; tir[mt * 4 + 1] = t4.y;
    tir[mt * 4 + 2] = t4.z; tir[mt * 4 + 3] = t4.w;
  }

  // orientation 1: rows of bi block, cols of bj block
  #pragma unroll
  for (int mt = 0; mt < 4; ++mt) {
    #pragma unroll
    for (int reg = 0; reg < 4; ++reg) {
      const int i = i0 + wr + mt * 16 + q * 4 + reg;
      const int ti = tir[mt * 4 + reg];
      float m = -1e30f, sn = 0.f;
      float sel[4];
      #pragma unroll
      for (int nt = 0; nt < 4; ++nt) {
        const float s = acc[mt][nt][reg];
        const int j = j0 + wc + nt * 16 + c;
        const bool same = (tj[nt] == ti);
        const bool vpos = same && (j != i);
        const float lp = (fminf(s, 1.25f) - 1.25f) * fmaf(s, 64.f, -48.f);
        const float sv = vpos ? lp : -2e30f;
        sel[nt] = sv;
        m = fmaxf(m, sv);
        const float ln = (fmaxf(s, -0.25f) + 0.25f) * fmaf(s, 64.f, -16.f);
        sn += same ? 0.f : __expf(ln);
      }
      #pragma unroll
      for (int off = 1; off < 16; off <<= 1) m = fmaxf(m, __shfl_xor(m, off));
      float sp = 0.f;
      #pragma unroll
      for (int nt = 0; nt < 4; ++nt) sp += __expf(sel[nt] - m);
      #pragma unroll
      for (int off = 1; off < 16; off <<= 1) {
        sp += __shfl_xor(sp, off);
        sn += __shfl_xor(sn, off);
      }
      if (c == 0) {
        float4 o; o.x = m; o.y = sp; o.z = 0.f; o.w = sn;
        partial[((size_t)i * nb + bj) * 2 + (w & 1)] = o;
      }
    }
  }

  // orientation 2: rows of bj block, cols of bi block (off-diagonal only)
  if (!isdiag) {
    #pragma unroll
    for (int nt = 0; nt < 4; ++nt) {
      const int jt = tj[nt];
      const int jrow = j0 + wc + nt * 16 + c;
      float m = -1e30f, sn = 0.f;
      float sel[16];
      #pragma unroll
      for (int mt = 0; mt < 4; ++mt) {
        #pragma unroll
        for (int reg = 0; reg < 4; ++reg) {
          const float s = acc[mt][nt][reg];
          const bool same = (tir[mt * 4 + reg] == jt);  // j != i off-diagonal
          const float lp = (fminf(s, 1.25f) - 1.25f) * fmaf(s, 64.f, -48.f);
          const float sv = same ? lp : -2e30f;
          sel[mt * 4 + reg] = sv;
          m = fmaxf(m, sv);
          const float ln = (fmaxf(s, -0.25f) + 0.25f) * fmaf(s, 64.f, -16.f);
          sn += same ? 0.f : __expf(ln);
        }
      }
      m = fmaxf(m, __shfl_xor(m, 16));
      m = fmaxf(m, __shfl_xor(m, 32));
      float sp = 0.f;
      #pragma unroll
      for (int k = 0; k < 16; ++k) sp += __expf(sel[k] - m);
      sp += __shfl_xor(sp, 16); sp += __shfl_xor(sp, 32);
      sn += __shfl_xor(sn, 16); sn += __shfl_xor(sn, 32);
      if (lane < 16) {
        float4 o; o.x = m; o.y = sp; o.z = 0.f; o.w = sn;
        partial[((size_t)jrow * nb + bi) * 2 + (w >> 1)] = o;
      }
    }
  }
}

// ---------------------------------------------------------------------------
// Kernel C: fold 128 partials per row -> row loss, then block-level masked
// sum + count, device-scope atomic accumulate, last-done block writes
// out[0] = sum / max(cnt, 1). One wave per row, 4 rows per block.
// ---------------------------------------------------------------------------
__global__ __launch_bounds__(THREADS) void k_reduce_final(const float4* __restrict__ partial,
                                                          float* __restrict__ accums,
                                                          float* __restrict__ out) {
  __shared__ float sl[4];
  const int tid = threadIdx.x;
  const int lane = tid & 63;
  const int wv = tid >> 6;
  const int row = blockIdx.x * 4 + wv;
  const float4 a = partial[(size_t)row * 128 + lane];
  const float4 b = partial[(size_t)row * 128 + 64 + lane];
  float mp = fmaxf(a.x, b.x);
  float sp = a.y * __expf(a.x - mp) + b.y * __expf(b.x - mp);
  float sn = a.w + b.w;
  #pragma unroll
  for (int off = 1; off < 64; off <<= 1) {
    const float m2 = __shfl_xor(mp, off), s2 = __shfl_xor(sp, off);
    const float nm = fmaxf(mp, m2);
    sp = sp * __expf(mp - nm) + s2 * __expf(m2 - nm);
    mp = nm;
    sn += __shfl_xor(sn, off);
  }
  if (lane == 0) {
    float loss = -1.0f;
    if (sp > 0.f && sn > 0.f) {
      const float z = mp + logf(sp) + logf(sn);
      loss = (z > 0.f) ? (z + log1pf(__expf(-z))) : log1pf(__expf(z));
    }
    sl[wv] = loss;
  }
  __syncthreads();
  if (tid == 0) {
    float bsum = 0.f, bcnt = 0.f;
    #pragma unroll
    for (int k = 0; k < 4; ++k) {
      const float l = sl[k];
      if (l >= 0.f) { bsum += l; bcnt += 1.f; }
    }
    atomicAdd(&accums[0], bsum);
    atomicAdd(&accums[1], bcnt);
    __threadfence();
    const int old = atomicAdd(reinterpret_cast<int*>(accums) + 2, 1);
    if (old == (int)gridDim.x - 1) {
      __threadfence();
      const float s = atomicAdd(&accums[0], 0.f);
      const float cnt = atomicAdd(&accums[1], 0.f);
      out[0] = s / fmaxf(cnt, 1.f);
    }
  }
}

// ---------------------------------------------------------------------------
extern "C" void kernel_launch(void* const* d_in, const int* in_sizes, int n_in,
                              void* d_out, int out_size, void* d_ws, size_t ws_size,
                              hipStream_t stream) {
  const float* x = (const float*)d_in[0];
  const int* tgt = (const int*)d_in[1];
  float* out = (float*)d_out;
  const int B = in_sizes[1];
  const int D = in_sizes[0] / B;
  const int nb = B / 128;   // 64

  ushortT* xn = (ushortT*)d_ws;                                   // B*D bf16 (16 MB)
  float4* partial = (float4*)((char*)d_ws + (size_t)B * D * 2);   // B*2*nb float4 (16 MB)
  float* accums = (float*)((char*)d_ws + (size_t)B * D * 2 + (size_t)B * 2 * nb * 16);

  k_prep<<<B, THREADS, 0, stream>>>(x, xn, accums, D);
  k_main_mfma<<<nb * (nb + 1) / 2, THREADS, 0, stream>>>(xn, tgt, partial, D, nb);
  k_reduce_final<<<B / 4, THREADS, 0, stream>>>(partial, accums, out);
}